// Round 1
// baseline (1150.000 us; speedup 1.0000x reference)
//
#include <hip/hip_runtime.h>
#include <cstdio>

#define EXPERTS 8
#define ODIM 4096
#define IDIM 1024
#define BATCH 16
#define SEQ 2048

#define BM 128
#define BN 128
#define BK 32
#define LDSS 40   // LDS row stride in bf16 elements (32 + 8 pad, keeps 16B alignment)

typedef __attribute__((ext_vector_type(8))) short bf16x8;
typedef __attribute__((ext_vector_type(4))) float f32x4;

__device__ __forceinline__ unsigned short to_bf16(float f) {
    union { float f; unsigned u; } v; v.f = f;
    return (unsigned short)((v.u + 0x8000u) >> 16);  // round-half-up, err <= 2^-9
}

__global__ __launch_bounds__(256)
void moe_gemm_kernel(const float* __restrict__ x,
                     const float* __restrict__ probs,
                     const float* __restrict__ w,
                     const float* __restrict__ bias,
                     float* __restrict__ out) {
    __shared__ unsigned short As[BM * LDSS];
    __shared__ unsigned short Bs[BN * LDSS];
    __shared__ int s_e;

    const int tn  = blockIdx.x;   // 0..31 -> n tile
    const int tm  = blockIdx.y;   // 0..15 -> m tile
    const int b   = blockIdx.z;   // 0..15 -> batch
    const int tid = threadIdx.x;

    // top-1 routing: argmax over 8 probs (first-max tiebreak like jnp.argmax)
    if (tid == 0) {
        float best = probs[b * EXPERTS];
        int bi = 0;
        #pragma unroll
        for (int e2 = 1; e2 < EXPERTS; ++e2) {
            float p = probs[b * EXPERTS + e2];
            if (p > best) { best = p; bi = e2; }
        }
        s_e = bi;
    }
    __syncthreads();
    const int e = s_e;

    const int m0 = tm * BM;
    const int n0 = tn * BN;

    // staging map: each thread loads 4 float4 per tile (row = tid/8 + 32*pass, col = (tid%8)*4)
    const int srow = tid >> 3;
    const int scol = (tid & 7) * 4;

    const float* ag = x + ((size_t)b * SEQ + m0 + srow) * IDIM + scol;
    const float* bg = w + ((size_t)e * ODIM + n0 + srow) * IDIM + scol;

    const int lane = tid & 63;
    const int wave = tid >> 6;
    const int wm = (wave & 1) * 64;   // wave row offset inside 128 tile
    const int wn = (wave >> 1) * 64;  // wave col offset
    const int frow = lane & 15;       // fragment row (A: m, B: n, C/D: col)
    const int fk   = (lane >> 4) * 8; // fragment k offset

    f32x4 acc[4][4];
    #pragma unroll
    for (int i = 0; i < 4; ++i)
        #pragma unroll
        for (int j = 0; j < 4; ++j)
            acc[i][j] = (f32x4){0.f, 0.f, 0.f, 0.f};

    for (int k0 = 0; k0 < IDIM; k0 += BK) {
        // ---- stage A,B tiles (fp32 -> bf16) ----
        #pragma unroll
        for (int p = 0; p < 4; ++p) {
            const f32x4 av = *(const f32x4*)(ag + (size_t)p * 32 * IDIM);
            const f32x4 bv = *(const f32x4*)(bg + (size_t)p * 32 * IDIM);
            const int r = srow + p * 32;
            union { unsigned short s[4]; unsigned long long u; } pa, pb;
            pa.s[0] = to_bf16(av.x); pa.s[1] = to_bf16(av.y);
            pa.s[2] = to_bf16(av.z); pa.s[3] = to_bf16(av.w);
            pb.s[0] = to_bf16(bv.x); pb.s[1] = to_bf16(bv.y);
            pb.s[2] = to_bf16(bv.z); pb.s[3] = to_bf16(bv.w);
            *(unsigned long long*)&As[r * LDSS + scol] = pa.u;
            *(unsigned long long*)&Bs[r * LDSS + scol] = pb.u;
        }
        __syncthreads();

        // ---- LDS -> fragments -> MFMA ----
        bf16x8 a_frag[4], b_frag[4];
        #pragma unroll
        for (int i = 0; i < 4; ++i)
            a_frag[i] = *(const bf16x8*)&As[(wm + i * 16 + frow) * LDSS + fk];
        #pragma unroll
        for (int j = 0; j < 4; ++j)
            b_frag[j] = *(const bf16x8*)&Bs[(wn + j * 16 + frow) * LDSS + fk];

        #pragma unroll
        for (int i = 0; i < 4; ++i)
            #pragma unroll
            for (int j = 0; j < 4; ++j)
                acc[i][j] = __builtin_amdgcn_mfma_f32_16x16x32_bf16(
                    a_frag[i], b_frag[j], acc[i][j], 0, 0, 0);
        __syncthreads();

        ag += BK;
        bg += BK;
    }

    // ---- epilogue: + bias, store fp32 ----
    // C/D layout: col = lane&15, row = (lane>>4)*4 + reg   [m89-verified]
    const float* bias_e = bias + (size_t)e * ODIM;
    const int rbase = (lane >> 4) * 4;
    #pragma unroll
    for (int j = 0; j < 4; ++j) {
        const int n = n0 + wn + j * 16 + frow;
        const float bv = bias_e[n];
        #pragma unroll
        for (int i = 0; i < 4; ++i) {
            const int mb = m0 + wm + i * 16 + rbase;
            float* op = out + ((size_t)b * SEQ + mb) * ODIM + n;
            #pragma unroll
            for (int r = 0; r < 4; ++r)
                op[(size_t)r * ODIM] = acc[i][j][r] + bv;
        }
    }
}

__global__ void moe_idx_kernel(const float* __restrict__ probs,
                               float* __restrict__ out_idx) {
    const int b = threadIdx.x;
    if (b < BATCH) {
        float best = probs[b * EXPERTS];
        int bi = 0;
        #pragma unroll
        for (int e2 = 1; e2 < EXPERTS; ++e2) {
            float p = probs[b * EXPERTS + e2];
            if (p > best) { best = p; bi = e2; }
        }
        out_idx[b] = (float)bi;
    }
}

extern "C" void kernel_launch(void* const* d_in, const int* in_sizes, int n_in,
                              void* d_out, int out_size, void* d_ws, size_t ws_size,
                              hipStream_t stream) {
    const float* x     = (const float*)d_in[0];
    const float* probs = (const float*)d_in[1];
    const float* w     = (const float*)d_in[2];
    const float* bias  = (const float*)d_in[3];
    float* out = (float*)d_out;

    // diagnostic for next rounds: can we pre-convert x/w to bf16 in d_ws?
    fprintf(stderr, "[kernel] ws_size=%zu out_size=%d\n", ws_size, out_size);

    dim3 grid(ODIM / BN, SEQ / BM, BATCH);   // 32 x 16 x 16 = 8192 blocks
    moe_gemm_kernel<<<grid, 256, 0, stream>>>(x, probs, w, bias, out);
    moe_idx_kernel<<<1, 64, 0, stream>>>(probs, out + (size_t)BATCH * SEQ * ODIM);
}